// Round 5
// baseline (183.360 us; speedup 1.0000x reference)
//
#include <hip/hip_runtime.h>
#include <stdint.h>

// AlbertSeq2Seq fused pipeline, bf16 MFMA. Round 5:
//  - Attention: S-split across waves (8-wave blocks: 4 q-subtiles x 2 s-halves),
//    fixed-shift softmax makes partials additive; combine via LDS at end.
//    Doubles waves/SIMD 2->4 to hide the QK->exp->PV dependency chain.
//  - GEMMs / cvt / transpose / LN unchanged.
// Shapes: B=4, T=S=1024, H=1024, heads=16, d=64.

#define B_   4
#define T_   1024
#define S_   1024
#define H_   1024
#define LOG2E 1.44269504088896340736f
#define SCALE_K (0.125f * LOG2E)

typedef __attribute__((ext_vector_type(8)))  __bf16       bf16x8;
typedef __attribute__((ext_vector_type(4)))  float        f32x4;
typedef __attribute__((ext_vector_type(16))) float        f32x16;
typedef __attribute__((ext_vector_type(4)))  unsigned int uint4v;

static __device__ __forceinline__ float bf2f(unsigned int u) {
    return __builtin_bit_cast(float, u << 16);
}
static __device__ __forceinline__ unsigned short f2bf(float f) {
    unsigned int x = __builtin_bit_cast(unsigned int, f);
    return (unsigned short)((x + 0x7fffu + ((x >> 16) & 1u)) >> 16);
}
static __device__ __forceinline__ unsigned int cvt_pk_bf16(float lo, float hi) {
    unsigned int r;
    asm("v_cvt_pk_bf16_f32 %0, %1, %2" : "=v"(r) : "v"(lo), "v"(hi));
    return r;
}
static __device__ __forceinline__ void perm32swap(unsigned int& a, unsigned int& b) {
    asm("v_permlane32_swap_b32 %0, %1" : "+v"(a), "+v"(b));
}
static __device__ __forceinline__ f32x4 mfma16(bf16x8 a, bf16x8 b, f32x4 c) {
    return __builtin_amdgcn_mfma_f32_16x16x32_bf16(a, b, c, 0, 0, 0);
}
static __device__ __forceinline__ f32x16 mfma32(bf16x8 a, bf16x8 b, f32x16 c) {
    return __builtin_amdgcn_mfma_f32_32x32x16_bf16(a, b, c, 0, 0, 0);
}

typedef const __attribute__((address_space(1))) void gv_t;
typedef __attribute__((address_space(3))) void lv_t;
static __device__ __forceinline__ void g2lds16(const void* g, void* l) {
    __builtin_amdgcn_global_load_lds((gv_t*)(size_t)g, (lv_t*)(unsigned int)(size_t)l, 16, 0, 0);
}

// ---------------- fused fp32 -> bf16 convert (6 tensors, 1 launch) ----------------
struct CvtArgs {
    const float* src[6];
    unsigned short* dst[6];
    float scale[6];
    int n4[6];
};
__global__ __launch_bounds__(256)
void cvt_multi(CvtArgs a) {
    const int k = blockIdx.y;
    const int i = blockIdx.x * 256 + threadIdx.x;
    if (i >= a.n4[k]) return;
    const float s = a.scale[k];
    float4 v = ((const float4*)a.src[k])[i];
    uint2 o;
    o.x = (unsigned)f2bf(v.x * s) | ((unsigned)f2bf(v.y * s) << 16);
    o.y = (unsigned)f2bf(v.z * s) | ((unsigned)f2bf(v.w * s) << 16);
    ((uint2*)a.dst[k])[i] = o;
}

// ---------------- GEMM: O[set] = A[set] @ W[set]^T + bias[set]*bs[set] ----------------
struct GemmJob {
    const unsigned short* A[5];
    const unsigned short* W[5];
    const float* bias[5];
    float bs[5];
    unsigned short* O[5];
};
__global__ __launch_bounds__(256, 2)
void gemm_bf16(GemmJob job)
{
    __shared__ char smem[32768];
    char* As = smem;
    char* Bs = smem + 16384;
    const int tid = threadIdx.x;
    const int lane = tid & 63;
    const int w = tid >> 6;
    const int c = lane & 15, g = lane >> 4;
    const int wm = (w >> 1) * 64, wn = (w & 1) * 64;
    const int m0 = blockIdx.x * 128;
    const int set = blockIdx.y >> 3;
    const int n0 = (blockIdx.y & 7) * 128;
    const unsigned short* A    = job.A[set];
    const unsigned short* W    = job.W[set];
    const float* bias          = job.bias[set];
    const float bscale         = job.bs[set];
    unsigned short* O          = job.O[set];

    f32x4 acc[4][4];
#pragma unroll
    for (int i = 0; i < 4; i++)
#pragma unroll
        for (int j = 0; j < 4; j++) acc[i][j] = (f32x4){0.f, 0.f, 0.f, 0.f};

    const int srow = w * 32 + (lane >> 3);
    const int swzc = ((lane & 7) ^ (lane >> 3)) * 8;
    const unsigned short* gA = A + (size_t)(m0 + srow) * 1024 + swzc;
    const unsigned short* gB = W + (size_t)(n0 + srow) * 1024 + swzc;
    char* lA = As + w * 4096;
    char* lB = Bs + w * 4096;

    for (int kk = 0; kk < 1024; kk += 64) {
#pragma unroll
        for (int q = 0; q < 4; q++) {
            g2lds16(gA + kk + q*8192, lA + q*1024);
            g2lds16(gB + kk + q*8192, lB + q*1024);
        }
        __syncthreads();
#pragma unroll
        for (int ksub = 0; ksub < 2; ksub++) {
            bf16x8 af[4], bfr[4];
#pragma unroll
            for (int t = 0; t < 4; t++) {
                const int ra = wm + t*16 + c;
                const int rb = wn + t*16 + c;
                const int so = ((ksub*4 + g) ^ (c & 7)) << 4;
                af[t]  = *(const bf16x8*)(As + ra*128 + so);
                bfr[t] = *(const bf16x8*)(Bs + rb*128 + so);
            }
#pragma unroll
            for (int i = 0; i < 4; i++)
#pragma unroll
                for (int j = 0; j < 4; j++)
                    acc[i][j] = mfma16(af[i], bfr[j], acc[i][j]);
        }
        __syncthreads();
    }

    float bvv[4];
#pragma unroll
    for (int j = 0; j < 4; j++) bvv[j] = bias[n0 + wn + j*16 + c] * bscale;
    char* eb = As + w * 4096;
#pragma unroll
    for (int p = 0; p < 2; p++) {
#pragma unroll
        for (int ii = 0; ii < 2; ii++) {
            const int i = p*2 + ii;
#pragma unroll
            for (int j = 0; j < 4; j++)
#pragma unroll
                for (int r = 0; r < 4; r++)
                    *(unsigned short*)(eb + (ii*16 + g*4 + r)*128 + (c + j*16)*2)
                        = f2bf(acc[i][j][r] + bvv[j]);
        }
        asm volatile("s_waitcnt lgkmcnt(0)" ::: "memory");
#pragma unroll
        for (int it = 0; it < 4; it++) {
            const int lrow = it*8 + (lane >> 3);
            uint4 vv = *(const uint4*)(eb + lrow*128 + (lane & 7)*16);
            *(uint4*)(O + (size_t)(m0 + wm + p*32 + lrow)*1024 + n0 + wn + (lane & 7)*8) = vv;
        }
        if (p == 0) asm volatile("s_waitcnt lgkmcnt(0)" ::: "memory");
    }
}

// ---------------- per-head V transpose (both tensors, one launch) ----------------
__global__ __launch_bounds__(256)
void transpose_v2(const unsigned short* __restrict__ V0, unsigned short* __restrict__ VT0,
                  const unsigned short* __restrict__ V1, unsigned short* __restrict__ VT1)
{
    __shared__ char sm[8192];
    const unsigned short* V = blockIdx.z ? V1 : V0;
    unsigned short* VT      = blockIdx.z ? VT1 : VT0;
    const int tid = threadIdx.x;
    const int bh = blockIdx.y, b = bh >> 4, h = bh & 15;
    const int s0 = blockIdx.x * 64;
    for (int u = tid; u < 512; u += 256) {
        const int r = u >> 3, sg = u & 7;
        uint4 v = *(const uint4*)(V + (size_t)(b*S_ + s0 + r)*H_ + h*64 + sg*8);
        *(uint4*)(sm + r*128 + ((sg*16) ^ ((r & 7) << 4))) = v;
    }
    __syncthreads();
    const int d = tid >> 2, ss = tid & 3;
    unsigned int ow[8];
#pragma unroll
    for (int j2 = 0; j2 < 8; j2++) {
        const int s_a = ss*16 + 2*j2, s_b = s_a + 1;
        unsigned int ta = *(const unsigned short*)(sm + s_a*128 + ((2*d) ^ ((s_a & 7) << 4)));
        unsigned int tb = *(const unsigned short*)(sm + s_b*128 + ((2*d) ^ ((s_b & 7) << 4)));
        ow[j2] = ta | (tb << 16);
    }
    unsigned short* op = VT + (size_t)(bh*64 + d)*S_ + s0 + ss*16;
    uint4 o0, o1;
    o0.x = ow[0]; o0.y = ow[1]; o0.z = ow[2]; o0.w = ow[3];
    o1.x = ow[4]; o1.y = ow[5]; o1.z = ow[6]; o1.w = ow[7];
    *(uint4*)op = o0;
    *(uint4*)(op + 8) = o1;
}

// ---------------- fused flash attention, round 5: S-split 8-wave blocks ----------------
// grid (T/128, B*NH), 512 threads = 8 waves: wg = w&3 picks q-subtile (32 rows),
// shalf = w>>2 picks K/V tile range (tiles 0-7 vs 8-15). Fixed-shift softmax
// (K pre-scaled by 0.125*log2e) => partial o / lsum are additive across s-halves.
// Per-shalf double-buffered K/V LDS (32KB each), 1 barrier/tile, DMA staging
// with pre-swizzled per-lane source. lsum via mfma(P, ones) in o's C-layout.
__global__ __launch_bounds__(512, 4)
void attn_fused4(const unsigned short* __restrict__ Q,
                 const unsigned short* __restrict__ Kx,
                 const unsigned short* __restrict__ VT,
                 const float* __restrict__ mask,
                 unsigned short* __restrict__ Octx)
{
    __shared__ char smem[65536 + 4096 + 16];
    float* mb = (float*)(smem + 65536);
    int* flag = (int*)(smem + 65536 + 4096);

    const int tid = threadIdx.x;
    const int lane = tid & 63, w = tid >> 6;
    const int wg = w & 3, shalf = w >> 2;
    const int qc = lane & 31, hi = lane >> 5;
    const int bh = blockIdx.y, b = bh >> 4, h = bh & 15;
    const int q0 = blockIdx.x * 128 + wg * 32;

    // staging: within the 4-wave group, thread-group-id tg covers rows 0..31 (+32 via 2nd DMA)
    const int tg = wg * 64 + lane;
    const int rs = tg >> 3, sg = tg & 7;
    const int scol = (sg ^ (rs & 7)) * 8;    // pre-swizzled source col: LDS[r][s]=G[r][s^(r&7)]
    const unsigned short* gK = Kx + (size_t)(b*S_ + shalf*512 + rs)*H_ + h*64 + scol;
    const unsigned short* gV = VT + (size_t)(bh*64 + rs)*S_ + shalf*512 + scol;
    char* sbase = smem + shalf * 32768;
    char* ldK = sbase + wg * 1024;           // + buf*16384
    char* ldV = sbase + 8192 + wg * 1024;

    // Q fragments: B[k=d][col=q]
    const unsigned short* qptr = Q + (size_t)(b*T_ + q0 + qc)*H_ + h*64 + hi*8;
    bf16x8 qf[4];
#pragma unroll
    for (int s = 0; s < 4; s++) qf[s] = *(const bf16x8*)(qptr + s*16);

    uint4v onesw;
    onesw[0] = 0x3f803f80u; onesw[1] = 0x3f803f80u; onesw[2] = 0x3f803f80u; onesw[3] = 0x3f803f80u;
    const bf16x8 ones = __builtin_bit_cast(bf16x8, onesw);

    if (tid == 0) *flag = 0;
    // tile 0 of this shalf -> buf 0
    g2lds16(gK,          ldK);
    g2lds16(gK + 32*H_,  ldK + 4096);
    g2lds16(gV,          ldV);
    g2lds16(gV + 32*S_,  ldV + 4096);
    __syncthreads();
    if (tid < 256) {
        float4 mv = ((const float4*)(mask + (size_t)b*S_))[tid];
        float4 ms;
        ms.x = mv.x * LOG2E; ms.y = mv.y * LOG2E; ms.z = mv.z * LOG2E; ms.w = mv.w * LOG2E;
        ((float4*)mb)[tid] = ms;
        if (mv.x != 0.f || mv.y != 0.f || mv.z != 0.f || mv.w != 0.f) atomicOr(flag, 1);
    }
    __syncthreads();
    const int msk = *flag;

    f32x16 o0 = {}, o1 = {}, lsum = {};

    for (int t = 0; t < 8; ++t) {
        if (t < 7) {
            const int nb = (t + 1) & 1;
            const size_t ko = (size_t)(t + 1) * 64 * H_;
            const int    vo = (t + 1) * 64;
            g2lds16(gK + ko,          ldK + nb*16384);
            g2lds16(gK + ko + 32*H_,  ldK + nb*16384 + 4096);
            g2lds16(gV + vo,          ldV + nb*16384);
            g2lds16(gV + vo + 32*S_,  ldV + nb*16384 + 4096);
        }
        const char* Ks = sbase + (t & 1) * 16384;
        const char* Vs = Ks + 8192;

#pragma unroll
        for (int ts = 0; ts < 2; ++ts) {
            // ---- QK^T ----
            f32x16 st = {};
            __builtin_amdgcn_s_setprio(1);
#pragma unroll
            for (int step = 0; step < 4; ++step) {
                bf16x8 ak = *(const bf16x8*)(Ks + (ts*32 + qc)*128 +
                             ((step*32 + hi*16) ^ ((qc & 7) << 4)));
                st = mfma32(ak, qf[step], st);
            }
            __builtin_amdgcn_s_setprio(0);

            // ---- softmax: P = exp2(S + mask*LOG2E), in place ----
            if (msk) {
#pragma unroll
                for (int rq = 0; rq < 4; ++rq) {
                    const float4 bb = *(const float4*)(mb + shalf*512 + t*64 + ts*32 + rq*8 + hi*4);
#pragma unroll
                    for (int e = 0; e < 4; ++e)
                        st[rq*4 + e] = __builtin_amdgcn_exp2f(st[rq*4 + e] + (&bb.x)[e]);
                }
            } else {
#pragma unroll
                for (int r = 0; r < 16; ++r) st[r] = __builtin_amdgcn_exp2f(st[r]);
            }

            // ---- P->A-frags (cvt_pk + permlane32_swap) + PV + l-sum ----
#pragma unroll
            for (int half = 0; half < 2; ++half) {
                unsigned w0 = cvt_pk_bf16(st[half*8 + 0], st[half*8 + 1]);
                unsigned w1 = cvt_pk_bf16(st[half*8 + 2], st[half*8 + 3]);
                unsigned w2 = cvt_pk_bf16(st[half*8 + 4], st[half*8 + 5]);
                unsigned w3 = cvt_pk_bf16(st[half*8 + 6], st[half*8 + 7]);
                perm32swap(w0, w2);
                perm32swap(w1, w3);
                uint4v fw; fw[0] = w0; fw[1] = w1; fw[2] = w2; fw[3] = w3;
                const bf16x8 pa = __builtin_bit_cast(bf16x8, fw);
                const int vcol = (ts*64 + half*32 + hi*16) ^ ((qc & 7) << 4);
                bf16x8 v0 = *(const bf16x8*)(Vs + qc*128        + vcol);
                bf16x8 v1 = *(const bf16x8*)(Vs + (32 + qc)*128 + vcol);
                __builtin_amdgcn_s_setprio(1);
                o0   = mfma32(pa, v0,   o0);
                o1   = mfma32(pa, v1,   o1);
                lsum = mfma32(pa, ones, lsum);
                __builtin_amdgcn_s_setprio(0);
            }
        }
        __syncthreads();   // drains this iter's DMA + protects dbuf reuse
    }

    // ---- combine s-halves via LDS (staging buffers are dead now) ----
    float* cb = (float*)smem;    // 4 waves x 64 lanes x 48 floats = 48KB
    if (shalf == 1) {
        float* dst = cb + wg*3072 + lane*48;
#pragma unroll
        for (int r = 0; r < 16; ++r) {
            dst[r]      = o0[r];
            dst[16 + r] = o1[r];
            dst[32 + r] = lsum[r];
        }
    }
    __syncthreads();
    if (shalf == 0) {
        const float* src = cb + wg*3072 + lane*48;
#pragma unroll
        for (int r = 0; r < 16; ++r) {
            o0[r]   += src[r];
            o1[r]   += src[16 + r];
            lsum[r] += src[32 + r];
        }
        // ---- normalize + store ----
#pragma unroll
        for (int dt = 0; dt < 2; ++dt) {
            const f32x16& oo = dt ? o1 : o0;
#pragma unroll
            for (int r = 0; r < 16; ++r) {
                const int qrow = (r & 3) + 8*(r >> 2) + 4*hi;
                const float val = oo[r] / lsum[r];
                Octx[(size_t)(b*T_ + q0 + qrow)*H_ + h*64 + dt*32 + qc] = f2bf(val);
            }
        }
    }
}

// ---------------- residual + LayerNorm ----------------
template<int OUTMODE>   // 0: bf16 out, 1: f32 out
__global__ __launch_bounds__(256)
void ln_kernel(const unsigned short* __restrict__ resid,
               const unsigned short* __restrict__ proj,
               const float* __restrict__ gam,
               const float* __restrict__ bet,
               unsigned short* __restrict__ obf,
               float* __restrict__ of32)
{
    __shared__ float red[8];
    const int tid = threadIdx.x;
    const int lane = tid & 63, w = tid >> 6;
    const int i = tid * 4;
    const size_t base = (size_t)blockIdx.x * 1024 + i;
    uint2 rv = *(const uint2*)(resid + base);
    uint2 pv = *(const uint2*)(proj + base);
    float x[4];
    x[0] = bf2f(rv.x & 0xffffu) + bf2f(pv.x & 0xffffu);
    x[1] = bf2f(rv.x >> 16)     + bf2f(pv.x >> 16);
    x[2] = bf2f(rv.y & 0xffffu) + bf2f(pv.y & 0xffffu);
    x[3] = bf2f(rv.y >> 16)     + bf2f(pv.y >> 16);
    float s = x[0] + x[1] + x[2] + x[3];
    float q = x[0]*x[0] + x[1]*x[1] + x[2]*x[2] + x[3]*x[3];
#pragma unroll
    for (int off = 1; off < 64; off <<= 1) {
        s += __shfl_xor(s, off);
        q += __shfl_xor(q, off);
    }
    if (lane == 0) { red[w*2] = s; red[w*2 + 1] = q; }
    __syncthreads();
    s = red[0] + red[2] + red[4] + red[6];
    q = red[1] + red[3] + red[5] + red[7];
    const float mu   = s * (1.f/1024.f);
    const float var  = q * (1.f/1024.f) - mu*mu;
    const float rstd = rsqrtf(var + 1e-12f);
    const float4 gv = *(const float4*)(gam + i);
    const float4 bv = *(const float4*)(bet + i);
    float y[4];
#pragma unroll
    for (int j = 0; j < 4; j++)
        y[j] = (x[j] - mu) * rstd * (&gv.x)[j] + (&bv.x)[j];
    if (OUTMODE == 0) {
        uint2 oo;
        oo.x = (unsigned)f2bf(y[0]) | ((unsigned)f2bf(y[1]) << 16);
        oo.y = (unsigned)f2bf(y[2]) | ((unsigned)f2bf(y[3]) << 16);
        *(uint2*)(obf + base) = oo;
    } else {
        float4 oo; oo.x = y[0]; oo.y = y[1]; oo.z = y[2]; oo.w = y[3];
        *(float4*)(of32 + base) = oo;
    }
}

extern "C" void kernel_launch(void* const* d_in, const int* in_sizes, int n_in,
                              void* d_out, int out_size, void* d_ws, size_t ws_size,
                              hipStream_t stream)
{
    const float* enc   = (const float*)d_in[0];
    const float* dec   = (const float*)d_in[1];
    const float* smask = (const float*)d_in[2];
    const float* tmask = (const float*)d_in[3];
    const float* Wq = (const float*)d_in[4];
    const float* bq = (const float*)d_in[5];
    const float* Wk = (const float*)d_in[6];
    const float* bk = (const float*)d_in[7];
    const float* Wv = (const float*)d_in[8];
    const float* bv = (const float*)d_in[9];
    const float* Wd = (const float*)d_in[10];
    const float* bd = (const float*)d_in[11];
    const float* lng = (const float*)d_in[12];
    const float* lnb = (const float*)d_in[13];
    float* out = (float*)d_out;

    char* ws = (char*)d_ws;
    const size_t MB = 1024ull * 1024ull;
    unsigned short* dec_bf = (unsigned short*)(ws + 0*MB);
    unsigned short* enc_bf = (unsigned short*)(ws + 8*MB);
    unsigned short* Wq_bf  = (unsigned short*)(ws + 16*MB);
    unsigned short* Wk_bf  = (unsigned short*)(ws + 18*MB);
    unsigned short* Wv_bf  = (unsigned short*)(ws + 20*MB);
    unsigned short* Wd_bf  = (unsigned short*)(ws + 22*MB);
    unsigned short* q1  = (unsigned short*)(ws + 24*MB);
    unsigned short* k1  = (unsigned short*)(ws + 32*MB);
    unsigned short* v1  = (unsigned short*)(ws + 40*MB);
    unsigned short* ek  = (unsigned short*)(ws + 48*MB);
    unsigned short* ev  = (unsigned short*)(ws + 56*MB);
    unsigned short* vt1 = (unsigned short*)(ws + 64*MB);
    unsigned short* ctx      = dec_bf;
    unsigned short* proj     = enc_bf;
    unsigned short* self_out = k1;
    unsigned short* evt      = v1;

    CvtArgs ca;
    ca.src[0] = dec; ca.dst[0] = dec_bf; ca.scale[0] = 1.f;      ca.n4[0] = 1048576;
    ca.src[1] = enc; ca.dst[1] = enc_bf; ca.scale[1] = 1.f;      ca.n4[1] = 1048576;
    ca.src[2] = Wq;  ca.dst[2] = Wq_bf;  ca.scale[2] = 1.f;      ca.n4[2] = 262144;
    ca.src[3] = Wk;  ca.dst[3] = Wk_bf;  ca.scale[3] = SCALE_K;  ca.n4[3] = 262144;
    ca.src[4] = Wv;  ca.dst[4] = Wv_bf;  ca.scale[4] = 1.f;      ca.n4[4] = 262144;
    ca.src[5] = Wd;  ca.dst[5] = Wd_bf;  ca.scale[5] = 1.f;      ca.n4[5] = 262144;
    cvt_multi<<<dim3(4096, 6), 256, 0, stream>>>(ca);

    GemmJob j1;
    j1.A[0] = dec_bf; j1.W[0] = Wq_bf; j1.bias[0] = bq; j1.bs[0] = 1.f;     j1.O[0] = q1;
    j1.A[1] = dec_bf; j1.W[1] = Wk_bf; j1.bias[1] = bk; j1.bs[1] = SCALE_K; j1.O[1] = k1;
    j1.A[2] = dec_bf; j1.W[2] = Wv_bf; j1.bias[2] = bv; j1.bs[2] = 1.f;     j1.O[2] = v1;
    j1.A[3] = enc_bf; j1.W[3] = Wk_bf; j1.bias[3] = bk; j1.bs[3] = SCALE_K; j1.O[3] = ek;
    j1.A[4] = enc_bf; j1.W[4] = Wv_bf; j1.bias[4] = bv; j1.bs[4] = 1.f;     j1.O[4] = ev;
    gemm_bf16<<<dim3(32, 40), 256, 0, stream>>>(j1);

    transpose_v2<<<dim3(16, 64, 2), 256, 0, stream>>>(v1, vt1, ev, evt);

    GemmJob jd;
    for (int i = 0; i < 5; i++) {
        jd.A[i] = ctx; jd.W[i] = Wd_bf; jd.bias[i] = bd; jd.bs[i] = 1.f; jd.O[i] = proj;
    }

    // self-attention
    attn_fused4<<<dim3(8, 64), 512, 0, stream>>>(q1, k1, vt1, tmask, ctx);
    gemm_bf16<<<dim3(32, 8), 256, 0, stream>>>(jd);
    ln_kernel<0><<<4096, 256, 0, stream>>>(q1, proj, lng, lnb, self_out, nullptr);

    // cross-attention (query = self_out directly)
    attn_fused4<<<dim3(8, 64), 512, 0, stream>>>(self_out, ek, evt, smask, ctx);
    gemm_bf16<<<dim3(32, 8), 256, 0, stream>>>(jd);
    ln_kernel<1><<<4096, 256, 0, stream>>>(self_out, proj, lng, lnb, nullptr, out);
}

// Round 6
// 168.650 us; speedup vs baseline: 1.0872x; 1.0872x over previous
//
#include <hip/hip_runtime.h>
#include <stdint.h>

// AlbertSeq2Seq fused pipeline, bf16 MFMA. Round 6:
//  - Attention reverted to round-3 version (reg-staged dbuf; R4/R5 DMA+S-split
//    variants were -7us regressions).
//  - Per-head V transpose fused into GEMM epilogue (sets with OT != null write
//    VT[(b*16+h)*64+d][s] directly via transposed LDS-bounce read); the
//    standalone transpose kernel and the v1/ev buffers are gone.
// Shapes: B=4, T=S=1024, H=1024, heads=16, d=64.

#define B_   4
#define T_   1024
#define S_   1024
#define H_   1024
#define LOG2E 1.44269504088896340736f
#define SCALE_K (0.125f * LOG2E)

typedef __attribute__((ext_vector_type(8)))  __bf16       bf16x8;
typedef __attribute__((ext_vector_type(4)))  float        f32x4;
typedef __attribute__((ext_vector_type(16))) float        f32x16;
typedef __attribute__((ext_vector_type(4)))  unsigned int uint4v;

static __device__ __forceinline__ float bf2f(unsigned int u) {
    return __builtin_bit_cast(float, u << 16);
}
static __device__ __forceinline__ unsigned short f2bf(float f) {
    unsigned int x = __builtin_bit_cast(unsigned int, f);
    return (unsigned short)((x + 0x7fffu + ((x >> 16) & 1u)) >> 16);
}
static __device__ __forceinline__ unsigned int cvt_pk_bf16(float lo, float hi) {
    unsigned int r;
    asm("v_cvt_pk_bf16_f32 %0, %1, %2" : "=v"(r) : "v"(lo), "v"(hi));
    return r;
}
static __device__ __forceinline__ void perm32swap(unsigned int& a, unsigned int& b) {
    asm("v_permlane32_swap_b32 %0, %1" : "+v"(a), "+v"(b));
}
static __device__ __forceinline__ f32x4 mfma16(bf16x8 a, bf16x8 b, f32x4 c) {
    return __builtin_amdgcn_mfma_f32_16x16x32_bf16(a, b, c, 0, 0, 0);
}
static __device__ __forceinline__ f32x16 mfma32(bf16x8 a, bf16x8 b, f32x16 c) {
    return __builtin_amdgcn_mfma_f32_32x32x16_bf16(a, b, c, 0, 0, 0);
}

typedef const __attribute__((address_space(1))) void gv_t;
typedef __attribute__((address_space(3))) void lv_t;
static __device__ __forceinline__ void g2lds16(const void* g, void* l) {
    __builtin_amdgcn_global_load_lds((gv_t*)(size_t)g, (lv_t*)(unsigned int)(size_t)l, 16, 0, 0);
}

// ---------------- fused fp32 -> bf16 convert (6 tensors, 1 launch) ----------------
struct CvtArgs {
    const float* src[6];
    unsigned short* dst[6];
    float scale[6];
    int n4[6];
};
__global__ __launch_bounds__(256)
void cvt_multi(CvtArgs a) {
    const int k = blockIdx.y;
    const int i = blockIdx.x * 256 + threadIdx.x;
    if (i >= a.n4[k]) return;
    const float s = a.scale[k];
    float4 v = ((const float4*)a.src[k])[i];
    uint2 o;
    o.x = (unsigned)f2bf(v.x * s) | ((unsigned)f2bf(v.y * s) << 16);
    o.y = (unsigned)f2bf(v.z * s) | ((unsigned)f2bf(v.w * s) << 16);
    ((uint2*)a.dst[k])[i] = o;
}

// ---------------- GEMM: O[set] = A[set] @ W[set]^T + bias[set]*bs[set] ----------------
// 128x128 tile, BK=64, 4 waves (2x2), each wave 64x64 = 4x4 frags of 16x16x32.
// If OT[set] != null, output is written per-head transposed:
//   OT[((m0/1024)*16 + n/64)*64 + n%64][m%1024] = C[m][n]   (V -> VT fusion).
struct GemmJob {
    const unsigned short* A[5];
    const unsigned short* W[5];
    const float* bias[5];
    float bs[5];
    unsigned short* O[5];
    unsigned short* OT[5];
};
__global__ __launch_bounds__(256, 2)
void gemm_bf16(GemmJob job)
{
    __shared__ char smem[32768];
    char* As = smem;
    char* Bs = smem + 16384;
    const int tid = threadIdx.x;
    const int lane = tid & 63;
    const int w = tid >> 6;
    const int c = lane & 15, g = lane >> 4;
    const int wm = (w >> 1) * 64, wn = (w & 1) * 64;
    const int m0 = blockIdx.x * 128;
    const int set = blockIdx.y >> 3;
    const int n0 = (blockIdx.y & 7) * 128;
    const unsigned short* A    = job.A[set];
    const unsigned short* W    = job.W[set];
    const float* bias          = job.bias[set];
    const float bscale         = job.bs[set];
    unsigned short* O          = job.O[set];
    unsigned short* OT         = job.OT[set];

    f32x4 acc[4][4];
#pragma unroll
    for (int i = 0; i < 4; i++)
#pragma unroll
        for (int j = 0; j < 4; j++) acc[i][j] = (f32x4){0.f, 0.f, 0.f, 0.f};

    const int srow = w * 32 + (lane >> 3);
    const int swzc = ((lane & 7) ^ (lane >> 3)) * 8;
    const unsigned short* gA = A + (size_t)(m0 + srow) * 1024 + swzc;
    const unsigned short* gB = W + (size_t)(n0 + srow) * 1024 + swzc;
    char* lA = As + w * 4096;
    char* lB = Bs + w * 4096;

    for (int kk = 0; kk < 1024; kk += 64) {
#pragma unroll
        for (int q = 0; q < 4; q++) {
            g2lds16(gA + kk + q*8192, lA + q*1024);
            g2lds16(gB + kk + q*8192, lB + q*1024);
        }
        __syncthreads();
#pragma unroll
        for (int ksub = 0; ksub < 2; ksub++) {
            bf16x8 af[4], bfr[4];
#pragma unroll
            for (int t = 0; t < 4; t++) {
                const int ra = wm + t*16 + c;
                const int rb = wn + t*16 + c;
                const int so = ((ksub*4 + g) ^ (c & 7)) << 4;
                af[t]  = *(const bf16x8*)(As + ra*128 + so);
                bfr[t] = *(const bf16x8*)(Bs + rb*128 + so);
            }
#pragma unroll
            for (int i = 0; i < 4; i++)
#pragma unroll
                for (int j = 0; j < 4; j++)
                    acc[i][j] = mfma16(af[i], bfr[j], acc[i][j]);
        }
        __syncthreads();
    }

    // epilogue: per-wave LDS bounce (4KB, 32 m-rows x 64 n-cols) per p-half
    float bvv[4];
#pragma unroll
    for (int j = 0; j < 4; j++) bvv[j] = bias[n0 + wn + j*16 + c] * bscale;
    char* eb = As + w * 4096;
#pragma unroll
    for (int p = 0; p < 2; p++) {
#pragma unroll
        for (int ii = 0; ii < 2; ii++) {
            const int i = p*2 + ii;
#pragma unroll
            for (int j = 0; j < 4; j++)
#pragma unroll
                for (int r = 0; r < 4; r++)
                    *(unsigned short*)(eb + (ii*16 + g*4 + r)*128 + (c + j*16)*2)
                        = f2bf(acc[i][j][r] + bvv[j]);
        }
        asm volatile("s_waitcnt lgkmcnt(0)" ::: "memory");
        if (OT == nullptr) {
            // natural coalesced store
#pragma unroll
            for (int it = 0; it < 4; it++) {
                const int lrow = it*8 + (lane >> 3);
                uint4 vv = *(const uint4*)(eb + lrow*128 + (lane & 7)*16);
                *(uint4*)(O + (size_t)(m0 + wm + p*32 + lrow)*1024 + n0 + wn + (lane & 7)*8) = vv;
            }
        } else {
            // transposed (V->VT) store: lane owns n-col (n0+wn+lane), reads its
            // column down 32 bounce rows, writes 32 contiguous s-elements.
            const int n_glob = n0 + wn + lane;
            const int hh = n_glob >> 6, dd = n_glob & 63;
            const int bidx = m0 >> 10;
            const int s_base = (m0 & 1023) + wm + p*32;
            unsigned short* vout = OT + ((size_t)((bidx*16 + hh)*64 + dd))*S_ + s_base;
            unsigned int pk[16];
#pragma unroll
            for (int r = 0; r < 16; r++) {
                unsigned int lo = *(const unsigned short*)(eb + (2*r    )*128 + lane*2);
                unsigned int hi = *(const unsigned short*)(eb + (2*r + 1)*128 + lane*2);
                pk[r] = lo | (hi << 16);
            }
#pragma unroll
            for (int q = 0; q < 4; q++) {
                uint4 vv;
                vv.x = pk[q*4 + 0]; vv.y = pk[q*4 + 1];
                vv.z = pk[q*4 + 2]; vv.w = pk[q*4 + 3];
                *(uint4*)(vout + q*8) = vv;
            }
        }
        if (p == 0) asm volatile("s_waitcnt lgkmcnt(0)" ::: "memory");
    }
}

// ---------------- fused flash attention (round-3 version, reg-staged dbuf) ----------------
// grid (T/128, B*NH), 256 threads = 4 waves, wave owns 32 q-rows.
// K pre-scaled by 0.125*log2e -> P = exp2(S^T) (fixed-shift softmax).
__global__ __launch_bounds__(256, 4)
void attn_fused2(const unsigned short* __restrict__ Q,
                 const unsigned short* __restrict__ Kx,
                 const unsigned short* __restrict__ VT,
                 const float* __restrict__ mask,
                 unsigned short* __restrict__ Octx)
{
    __shared__ char smem[32768 + 4096 + 512 + 16];
    float* mb   = (float*)(smem + 32768);
    float* lbuf = (float*)(smem + 32768 + 4096);
    int* flag   = (int*)(smem + 32768 + 4096 + 512);

    const int tid = threadIdx.x;
    const int lane = tid & 63, w = tid >> 6;
    const int qc = lane & 31, hi = lane >> 5;
    const int bh = blockIdx.y, b = bh >> 4, h = bh & 15;
    const int q0 = blockIdx.x * 128 + w * 32;

    const int r0 = tid >> 3, sg = tid & 7;
    const unsigned short* gK0 = Kx + (size_t)(b*S_ + r0)*H_  + h*64 + sg*8;
    const unsigned short* gK1 = gK0 + (size_t)32*H_;
    const unsigned short* gV0 = VT + (size_t)(bh*64 + r0)*S_ + sg*8;
    const unsigned short* gV1 = gV0 + (size_t)32*S_;
    const int woff = r0*128 + ((sg*16) ^ ((r0 & 7) << 4));

    const unsigned short* qptr = Q + (size_t)(b*T_ + q0 + qc)*H_ + h*64 + hi*8;
    bf16x8 qf[4];
#pragma unroll
    for (int s = 0; s < 4; s++) qf[s] = *(const bf16x8*)(qptr + s*16);

    // tile 0 staging
    uint4 cK0 = *(const uint4*)gK0;
    uint4 cK1 = *(const uint4*)gK1;
    uint4 cV0 = *(const uint4*)gV0;
    uint4 cV1 = *(const uint4*)gV1;

    if (tid == 0) *flag = 0;
    __syncthreads();
    {
        float4 mv = ((const float4*)(mask + (size_t)b*S_))[tid];
        float4 ms;
        ms.x = mv.x * LOG2E; ms.y = mv.y * LOG2E; ms.z = mv.z * LOG2E; ms.w = mv.w * LOG2E;
        ((float4*)mb)[tid] = ms;
        if (mv.x != 0.f || mv.y != 0.f || mv.z != 0.f || mv.w != 0.f) atomicOr(flag, 1);
    }
    {
        char* b0 = smem;
        *(uint4*)(b0 + woff)               = cK0;
        *(uint4*)(b0 + 4096 + woff)        = cK1;
        *(uint4*)(b0 + 8192 + woff)        = cV0;
        *(uint4*)(b0 + 8192 + 4096 + woff) = cV1;
    }
    __syncthreads();
    const int msk = *flag;

    f32x16 o0 = {}, o1 = {};
    float lacc = 0.f;

    for (int t = 0; t < 16; ++t) {
        uint4 nK0, nK1, nV0, nV1;
        if (t < 15) {
            const size_t ko = (size_t)(t + 1) * 64 * H_;
            const int    vo = (t + 1) * 64;
            nK0 = *(const uint4*)(gK0 + ko);
            nK1 = *(const uint4*)(gK1 + ko);
            nV0 = *(const uint4*)(gV0 + vo);
            nV1 = *(const uint4*)(gV1 + vo);
        }
        char* Ks = smem + (t & 1) * 16384;
        char* Vs = Ks + 8192;

#pragma unroll
        for (int ts = 0; ts < 2; ++ts) {
            // ---- QK^T ----
            f32x16 st = {};
            __builtin_amdgcn_s_setprio(1);
#pragma unroll
            for (int step = 0; step < 4; ++step) {
                bf16x8 ak = *(const bf16x8*)(Ks + (ts*32 + qc)*128 +
                             ((step*32 + hi*16) ^ ((qc & 7) << 4)));
                st = mfma32(ak, qf[step], st);
            }
            __builtin_amdgcn_s_setprio(0);

            // ---- softmax ----
            float pv[16];
            if (msk) {
#pragma unroll
                for (int rq = 0; rq < 4; ++rq) {
                    const float4 bb = *(const float4*)(mb + t*64 + ts*32 + rq*8 + hi*4);
#pragma unroll
                    for (int e = 0; e < 4; ++e)
                        pv[rq*4 + e] = __builtin_amdgcn_exp2f(st[rq*4 + e] + (&bb.x)[e]);
                }
            } else {
#pragma unroll
                for (int r = 0; r < 16; ++r) pv[r] = __builtin_amdgcn_exp2f(st[r]);
            }
#pragma unroll
            for (int r = 0; r < 16; ++r) lacc += pv[r];

            // ---- P->A-frags (cvt_pk + permlane32_swap) + PV ----
#pragma unroll
            for (int half = 0; half < 2; ++half) {
                unsigned w0 = cvt_pk_bf16(pv[half*8 + 0], pv[half*8 + 1]);
                unsigned w1 = cvt_pk_bf16(pv[half*8 + 2], pv[half*8 + 3]);
                unsigned w2 = cvt_pk_bf16(pv[half*8 + 4], pv[half*8 + 5]);
                unsigned w3 = cvt_pk_bf16(pv[half*8 + 6], pv[half*8 + 7]);
                perm32swap(w0, w2);
                perm32swap(w1, w3);
                uint4v fw; fw[0] = w0; fw[1] = w1; fw[2] = w2; fw[3] = w3;
                const bf16x8 pa = __builtin_bit_cast(bf16x8, fw);
                const int scol = (ts*64 + half*32 + hi*16) ^ ((qc & 7) << 4);
                bf16x8 v0 = *(const bf16x8*)(Vs + qc*128        + scol);
                bf16x8 v1 = *(const bf16x8*)(Vs + (32 + qc)*128 + scol);
                __builtin_amdgcn_s_setprio(1);
                o0 = mfma32(pa, v0, o0);
                o1 = mfma32(pa, v1, o1);
                __builtin_amdgcn_s_setprio(0);
            }
        }

        if (t < 15) {
            char* nxt = smem + ((t + 1) & 1) * 16384;
            *(uint4*)(nxt + woff)               = nK0;
            *(uint4*)(nxt + 4096 + woff)        = nK1;
            *(uint4*)(nxt + 8192 + woff)        = nV0;
            *(uint4*)(nxt + 8192 + 4096 + woff) = nV1;
        }
        __syncthreads();
    }

    // ---- epilogue ----
    {
        unsigned la = __builtin_bit_cast(unsigned, lacc);
        unsigned lb = la;
        perm32swap(la, lb);
        const float ltot = __builtin_bit_cast(float, la) + __builtin_bit_cast(float, lb);
        const float linv = 1.f / ltot;
        if (hi == 0) lbuf[w*32 + qc] = linv;
    }
    __syncthreads();
    float4 li[4];
#pragma unroll
    for (int rq = 0; rq < 4; ++rq)
        li[rq] = *(const float4*)(lbuf + w*32 + rq*8 + hi*4);

#pragma unroll
    for (int dt = 0; dt < 2; ++dt) {
        const f32x16& oo = dt ? o1 : o0;
#pragma unroll
        for (int r = 0; r < 16; ++r) {
            const int qrow = (r & 3) + 8*(r >> 2) + 4*hi;
            const float val = oo[r] * (&li[r >> 2].x)[r & 3];
            Octx[(size_t)(b*T_ + q0 + qrow)*H_ + h*64 + dt*32 + qc] = f2bf(val);
        }
    }
}

// ---------------- residual + LayerNorm ----------------
template<int OUTMODE>   // 0: bf16 out, 1: f32 out
__global__ __launch_bounds__(256)
void ln_kernel(const unsigned short* __restrict__ resid,
               const unsigned short* __restrict__ proj,
               const float* __restrict__ gam,
               const float* __restrict__ bet,
               unsigned short* __restrict__ obf,
               float* __restrict__ of32)
{
    __shared__ float red[8];
    const int tid = threadIdx.x;
    const int lane = tid & 63, w = tid >> 6;
    const int i = tid * 4;
    const size_t base = (size_t)blockIdx.x * 1024 + i;
    uint2 rv = *(const uint2*)(resid + base);
    uint2 pv = *(const uint2*)(proj + base);
    float x[4];
    x[0] = bf2f(rv.x & 0xffffu) + bf2f(pv.x & 0xffffu);
    x[1] = bf2f(rv.x >> 16)     + bf2f(pv.x >> 16);
    x[2] = bf2f(rv.y & 0xffffu) + bf2f(pv.y & 0xffffu);
    x[3] = bf2f(rv.y >> 16)     + bf2f(pv.y >> 16);
    float s = x[0] + x[1] + x[2] + x[3];
    float q = x[0]*x[0] + x[1]*x[1] + x[2]*x[2] + x[3]*x[3];
#pragma unroll
    for (int off = 1; off < 64; off <<= 1) {
        s += __shfl_xor(s, off);
        q += __shfl_xor(q, off);
    }
    if (lane == 0) { red[w*2] = s; red[w*2 + 1] = q; }
    __syncthreads();
    s = red[0] + red[2] + red[4] + red[6];
    q = red[1] + red[3] + red[5] + red[7];
    const float mu   = s * (1.f/1024.f);
    const float var  = q * (1.f/1024.f) - mu*mu;
    const float rstd = rsqrtf(var + 1e-12f);
    const float4 gv = *(const float4*)(gam + i);
    const float4 bv = *(const float4*)(bet + i);
    float y[4];
#pragma unroll
    for (int j = 0; j < 4; j++)
        y[j] = (x[j] - mu) * rstd * (&gv.x)[j] + (&bv.x)[j];
    if (OUTMODE == 0) {
        uint2 oo;
        oo.x = (unsigned)f2bf(y[0]) | ((unsigned)f2bf(y[1]) << 16);
        oo.y = (unsigned)f2bf(y[2]) | ((unsigned)f2bf(y[3]) << 16);
        *(uint2*)(obf + base) = oo;
    } else {
        float4 oo; oo.x = y[0]; oo.y = y[1]; oo.z = y[2]; oo.w = y[3];
        *(float4*)(of32 + base) = oo;
    }
}

extern "C" void kernel_launch(void* const* d_in, const int* in_sizes, int n_in,
                              void* d_out, int out_size, void* d_ws, size_t ws_size,
                              hipStream_t stream)
{
    const float* enc   = (const float*)d_in[0];
    const float* dec   = (const float*)d_in[1];
    const float* smask = (const float*)d_in[2];
    const float* tmask = (const float*)d_in[3];
    const float* Wq = (const float*)d_in[4];
    const float* bq = (const float*)d_in[5];
    const float* Wk = (const float*)d_in[6];
    const float* bk = (const float*)d_in[7];
    const float* Wv = (const float*)d_in[8];
    const float* bv = (const float*)d_in[9];
    const float* Wd = (const float*)d_in[10];
    const float* bd = (const float*)d_in[11];
    const float* lng = (const float*)d_in[12];
    const float* lnb = (const float*)d_in[13];
    float* out = (float*)d_out;

    char* ws = (char*)d_ws;
    const size_t MB = 1024ull * 1024ull;
    unsigned short* dec_bf = (unsigned short*)(ws + 0*MB);
    unsigned short* enc_bf = (unsigned short*)(ws + 8*MB);
    unsigned short* Wq_bf  = (unsigned short*)(ws + 16*MB);
    unsigned short* Wk_bf  = (unsigned short*)(ws + 18*MB);
    unsigned short* Wv_bf  = (unsigned short*)(ws + 20*MB);
    unsigned short* Wd_bf  = (unsigned short*)(ws + 22*MB);
    unsigned short* q1  = (unsigned short*)(ws + 24*MB);
    unsigned short* k1  = (unsigned short*)(ws + 32*MB);
    unsigned short* vt1 = (unsigned short*)(ws + 40*MB);
    unsigned short* ek  = (unsigned short*)(ws + 48*MB);
    unsigned short* evt = (unsigned short*)(ws + 56*MB);
    unsigned short* ctx      = dec_bf;   // dec_bf dead after j1
    unsigned short* proj     = enc_bf;   // enc_bf dead after j1
    unsigned short* self_out = k1;       // k1 dead after attn1

    CvtArgs ca;
    ca.src[0] = dec; ca.dst[0] = dec_bf; ca.scale[0] = 1.f;      ca.n4[0] = 1048576;
    ca.src[1] = enc; ca.dst[1] = enc_bf; ca.scale[1] = 1.f;      ca.n4[1] = 1048576;
    ca.src[2] = Wq;  ca.dst[2] = Wq_bf;  ca.scale[2] = 1.f;      ca.n4[2] = 262144;
    ca.src[3] = Wk;  ca.dst[3] = Wk_bf;  ca.scale[3] = SCALE_K;  ca.n4[3] = 262144;
    ca.src[4] = Wv;  ca.dst[4] = Wv_bf;  ca.scale[4] = 1.f;      ca.n4[4] = 262144;
    ca.src[5] = Wd;  ca.dst[5] = Wd_bf;  ca.scale[5] = 1.f;      ca.n4[5] = 262144;
    cvt_multi<<<dim3(4096, 6), 256, 0, stream>>>(ca);

    // merged projections: v-sets write per-head-transposed VT directly
    GemmJob j1;
    j1.A[0] = dec_bf; j1.W[0] = Wq_bf; j1.bias[0] = bq; j1.bs[0] = 1.f;     j1.O[0] = q1; j1.OT[0] = nullptr;
    j1.A[1] = dec_bf; j1.W[1] = Wk_bf; j1.bias[1] = bk; j1.bs[1] = SCALE_K; j1.O[1] = k1; j1.OT[1] = nullptr;
    j1.A[2] = dec_bf; j1.W[2] = Wv_bf; j1.bias[2] = bv; j1.bs[2] = 1.f;     j1.O[2] = nullptr; j1.OT[2] = vt1;
    j1.A[3] = enc_bf; j1.W[3] = Wk_bf; j1.bias[3] = bk; j1.bs[3] = SCALE_K; j1.O[3] = ek; j1.OT[3] = nullptr;
    j1.A[4] = enc_bf; j1.W[4] = Wv_bf; j1.bias[4] = bv; j1.bs[4] = 1.f;     j1.O[4] = nullptr; j1.OT[4] = evt;
    gemm_bf16<<<dim3(32, 40), 256, 0, stream>>>(j1);

    GemmJob jd;
    for (int i = 0; i < 5; i++) {
        jd.A[i] = ctx; jd.W[i] = Wd_bf; jd.bias[i] = bd; jd.bs[i] = 1.f;
        jd.O[i] = proj; jd.OT[i] = nullptr;
    }

    // self-attention
    attn_fused2<<<dim3(8, 64), 256, 0, stream>>>(q1, k1, vt1, tmask, ctx);
    gemm_bf16<<<dim3(32, 8), 256, 0, stream>>>(jd);
    ln_kernel<0><<<4096, 256, 0, stream>>>(q1, proj, lng, lnb, self_out, nullptr);

    // cross-attention (query = self_out directly)
    attn_fused2<<<dim3(8, 64), 256, 0, stream>>>(self_out, ek, evt, smask, ctx);
    gemm_bf16<<<dim3(32, 8), 256, 0, stream>>>(jd);
    ln_kernel<1><<<4096, 256, 0, stream>>>(self_out, proj, lng, lnb, nullptr, out);
}

// Round 7
// 165.898 us; speedup vs baseline: 1.1053x; 1.0166x over previous
//
#include <hip/hip_runtime.h>
#include <stdint.h>

// AlbertSeq2Seq fused pipeline, bf16 MFMA. Round 7:
//  - Attention grid reshaped to (bh=64, qtile=8): all 8 q-tile blocks of one
//    (b,h) land on the same XCD (linear id % 8 == bh % 8) -> K/V L2 reuse,
//    fixing the 4.3x HBM fetch amplification (68MB -> ~16MB distinct).
//  - GEMM OT (V->VT) epilogue: transposed LDS bounce ebT[n][m], pitch 72B,
//    b64 writes/reads instead of 64 scalar u16 ops per lane.
// Shapes: B=4, T=S=1024, H=1024, heads=16, d=64.

#define B_   4
#define T_   1024
#define S_   1024
#define H_   1024
#define LOG2E 1.44269504088896340736f
#define SCALE_K (0.125f * LOG2E)

typedef __attribute__((ext_vector_type(8)))  __bf16       bf16x8;
typedef __attribute__((ext_vector_type(4)))  float        f32x4;
typedef __attribute__((ext_vector_type(16))) float        f32x16;
typedef __attribute__((ext_vector_type(4)))  unsigned int uint4v;

static __device__ __forceinline__ float bf2f(unsigned int u) {
    return __builtin_bit_cast(float, u << 16);
}
static __device__ __forceinline__ unsigned short f2bf(float f) {
    unsigned int x = __builtin_bit_cast(unsigned int, f);
    return (unsigned short)((x + 0x7fffu + ((x >> 16) & 1u)) >> 16);
}
static __device__ __forceinline__ unsigned int cvt_pk_bf16(float lo, float hi) {
    unsigned int r;
    asm("v_cvt_pk_bf16_f32 %0, %1, %2" : "=v"(r) : "v"(lo), "v"(hi));
    return r;
}
static __device__ __forceinline__ void perm32swap(unsigned int& a, unsigned int& b) {
    asm("v_permlane32_swap_b32 %0, %1" : "+v"(a), "+v"(b));
}
static __device__ __forceinline__ f32x4 mfma16(bf16x8 a, bf16x8 b, f32x4 c) {
    return __builtin_amdgcn_mfma_f32_16x16x32_bf16(a, b, c, 0, 0, 0);
}
static __device__ __forceinline__ f32x16 mfma32(bf16x8 a, bf16x8 b, f32x16 c) {
    return __builtin_amdgcn_mfma_f32_32x32x16_bf16(a, b, c, 0, 0, 0);
}

typedef const __attribute__((address_space(1))) void gv_t;
typedef __attribute__((address_space(3))) void lv_t;
static __device__ __forceinline__ void g2lds16(const void* g, void* l) {
    __builtin_amdgcn_global_load_lds((gv_t*)(size_t)g, (lv_t*)(unsigned int)(size_t)l, 16, 0, 0);
}

// ---------------- fused fp32 -> bf16 convert (6 tensors, 1 launch) ----------------
struct CvtArgs {
    const float* src[6];
    unsigned short* dst[6];
    float scale[6];
    int n4[6];
};
__global__ __launch_bounds__(256)
void cvt_multi(CvtArgs a) {
    const int k = blockIdx.y;
    const int i = blockIdx.x * 256 + threadIdx.x;
    if (i >= a.n4[k]) return;
    const float s = a.scale[k];
    float4 v = ((const float4*)a.src[k])[i];
    uint2 o;
    o.x = (unsigned)f2bf(v.x * s) | ((unsigned)f2bf(v.y * s) << 16);
    o.y = (unsigned)f2bf(v.z * s) | ((unsigned)f2bf(v.w * s) << 16);
    ((uint2*)a.dst[k])[i] = o;
}

// ---------------- GEMM: O[set] = A[set] @ W[set]^T + bias[set]*bs[set] ----------------
// 128x128 tile, BK=64, 4 waves (2x2), each wave 64x64 = 4x4 frags of 16x16x32.
// If OT[set] != null, output is written per-head transposed:
//   OT[((m0/1024)*16 + n/64)*64 + n%64][m%1024] = C[m][n]   (V -> VT fusion).
struct GemmJob {
    const unsigned short* A[5];
    const unsigned short* W[5];
    const float* bias[5];
    float bs[5];
    unsigned short* O[5];
    unsigned short* OT[5];
};
__global__ __launch_bounds__(256, 2)
void gemm_bf16(GemmJob job)
{
    __shared__ char smem[32768];
    char* As = smem;
    char* Bs = smem + 16384;
    const int tid = threadIdx.x;
    const int lane = tid & 63;
    const int w = tid >> 6;
    const int c = lane & 15, g = lane >> 4;
    const int wm = (w >> 1) * 64, wn = (w & 1) * 64;
    const int m0 = blockIdx.x * 128;
    const int set = blockIdx.y >> 3;
    const int n0 = (blockIdx.y & 7) * 128;
    const unsigned short* A    = job.A[set];
    const unsigned short* W    = job.W[set];
    const float* bias          = job.bias[set];
    const float bscale         = job.bs[set];
    unsigned short* O          = job.O[set];
    unsigned short* OT         = job.OT[set];

    f32x4 acc[4][4];
#pragma unroll
    for (int i = 0; i < 4; i++)
#pragma unroll
        for (int j = 0; j < 4; j++) acc[i][j] = (f32x4){0.f, 0.f, 0.f, 0.f};

    const int srow = w * 32 + (lane >> 3);
    const int swzc = ((lane & 7) ^ (lane >> 3)) * 8;
    const unsigned short* gA = A + (size_t)(m0 + srow) * 1024 + swzc;
    const unsigned short* gB = W + (size_t)(n0 + srow) * 1024 + swzc;
    char* lA = As + w * 4096;
    char* lB = Bs + w * 4096;

    for (int kk = 0; kk < 1024; kk += 64) {
#pragma unroll
        for (int q = 0; q < 4; q++) {
            g2lds16(gA + kk + q*8192, lA + q*1024);
            g2lds16(gB + kk + q*8192, lB + q*1024);
        }
        __syncthreads();
#pragma unroll
        for (int ksub = 0; ksub < 2; ksub++) {
            bf16x8 af[4], bfr[4];
#pragma unroll
            for (int t = 0; t < 4; t++) {
                const int ra = wm + t*16 + c;
                const int rb = wn + t*16 + c;
                const int so = ((ksub*4 + g) ^ (c & 7)) << 4;
                af[t]  = *(const bf16x8*)(As + ra*128 + so);
                bfr[t] = *(const bf16x8*)(Bs + rb*128 + so);
            }
#pragma unroll
            for (int i = 0; i < 4; i++)
#pragma unroll
                for (int j = 0; j < 4; j++)
                    acc[i][j] = mfma16(af[i], bfr[j], acc[i][j]);
        }
        __syncthreads();
    }

    float bvv[4];
#pragma unroll
    for (int j = 0; j < 4; j++) bvv[j] = bias[n0 + wn + j*16 + c] * bscale;

    if (OT == nullptr) {
        // natural coalesced store via per-wave LDS bounce (4KB region)
        char* eb = As + w * 4096;
#pragma unroll
        for (int p = 0; p < 2; p++) {
#pragma unroll
            for (int ii = 0; ii < 2; ii++) {
                const int i = p*2 + ii;
#pragma unroll
                for (int j = 0; j < 4; j++)
#pragma unroll
                    for (int r = 0; r < 4; r++)
                        *(unsigned short*)(eb + (ii*16 + g*4 + r)*128 + (c + j*16)*2)
                            = f2bf(acc[i][j][r] + bvv[j]);
            }
            asm volatile("s_waitcnt lgkmcnt(0)" ::: "memory");
#pragma unroll
            for (int it = 0; it < 4; it++) {
                const int lrow = it*8 + (lane >> 3);
                uint4 vv = *(const uint4*)(eb + lrow*128 + (lane & 7)*16);
                *(uint4*)(O + (size_t)(m0 + wm + p*32 + lrow)*1024 + n0 + wn + (lane & 7)*8) = vv;
            }
            if (p == 0) asm volatile("s_waitcnt lgkmcnt(0)" ::: "memory");
        }
    } else {
        // transposed (V->VT) store via transposed bounce ebT[n_local(64)][m_local(32)],
        // pitch 72B (4-way max bank conflict), b64 writes (r-quad contiguous in m)
        // and b64 reads (lane streams its n-column's 32 m-values).
        char* ebT = smem + w * 8192;     // 64*72 = 4608 <= 8192, all smem free here
        const int n_glob = n0 + wn + lane;
        const int hh = n_glob >> 6, dd = n_glob & 63;
        const int bidx = m0 >> 10;
        unsigned short* vout0 = OT + ((size_t)((bidx*16 + hh)*64 + dd))*S_ + (m0 & 1023) + wm;
#pragma unroll
        for (int p = 0; p < 2; p++) {
#pragma unroll
            for (int ii = 0; ii < 2; ii++) {
                const int i = p*2 + ii;
#pragma unroll
                for (int j = 0; j < 4; j++) {
                    uint2 pw;
                    pw.x = (unsigned)f2bf(acc[i][j][0] + bvv[j]) |
                           ((unsigned)f2bf(acc[i][j][1] + bvv[j]) << 16);
                    pw.y = (unsigned)f2bf(acc[i][j][2] + bvv[j]) |
                           ((unsigned)f2bf(acc[i][j][3] + bvv[j]) << 16);
                    *(uint2*)(ebT + (j*16 + c)*72 + (ii*16 + g*4)*2) = pw;
                }
            }
            asm volatile("s_waitcnt lgkmcnt(0)" ::: "memory");
            unsigned short* vout = vout0 + p*32;
#pragma unroll
            for (int q = 0; q < 4; q++) {
                uint2 r0 = *(const uint2*)(ebT + lane*72 + (q*2    )*8);
                uint2 r1 = *(const uint2*)(ebT + lane*72 + (q*2 + 1)*8);
                uint4 vv; vv.x = r0.x; vv.y = r0.y; vv.z = r1.x; vv.w = r1.y;
                *(uint4*)(vout + q*8) = vv;
            }
            if (p == 0) asm volatile("s_waitcnt lgkmcnt(0)" ::: "memory");
        }
    }
}

// ---------------- fused flash attention (R3 structure, XCD-colocated grid) ----------------
// grid (B*NH=64, T/128=8), 256 threads = 4 waves, wave owns 32 q-rows.
// Linear block id = bh + 64*qt -> XCD = bh%8: all q-tiles of one (b,h) share an
// XCD so K/V (256KB) is fetched once per XCD, not 8x.
// K pre-scaled by 0.125*log2e -> P = exp2(S^T) (fixed-shift softmax).
__global__ __launch_bounds__(256, 4)
void attn_fused2(const unsigned short* __restrict__ Q,
                 const unsigned short* __restrict__ Kx,
                 const unsigned short* __restrict__ VT,
                 const float* __restrict__ mask,
                 unsigned short* __restrict__ Octx)
{
    __shared__ char smem[32768 + 4096 + 512 + 16];
    float* mb   = (float*)(smem + 32768);
    float* lbuf = (float*)(smem + 32768 + 4096);
    int* flag   = (int*)(smem + 32768 + 4096 + 512);

    const int tid = threadIdx.x;
    const int lane = tid & 63, w = tid >> 6;
    const int qc = lane & 31, hi = lane >> 5;
    const int bh = blockIdx.x, b = bh >> 4, h = bh & 15;
    const int q0 = blockIdx.y * 128 + w * 32;

    const int r0 = tid >> 3, sg = tid & 7;
    const unsigned short* gK0 = Kx + (size_t)(b*S_ + r0)*H_  + h*64 + sg*8;
    const unsigned short* gK1 = gK0 + (size_t)32*H_;
    const unsigned short* gV0 = VT + (size_t)(bh*64 + r0)*S_ + sg*8;
    const unsigned short* gV1 = gV0 + (size_t)32*S_;
    const int woff = r0*128 + ((sg*16) ^ ((r0 & 7) << 4));

    const unsigned short* qptr = Q + (size_t)(b*T_ + q0 + qc)*H_ + h*64 + hi*8;
    bf16x8 qf[4];
#pragma unroll
    for (int s = 0; s < 4; s++) qf[s] = *(const bf16x8*)(qptr + s*16);

    // tile 0 staging
    uint4 cK0 = *(const uint4*)gK0;
    uint4 cK1 = *(const uint4*)gK1;
    uint4 cV0 = *(const uint4*)gV0;
    uint4 cV1 = *(const uint4*)gV1;

    if (tid == 0) *flag = 0;
    __syncthreads();
    {
        float4 mv = ((const float4*)(mask + (size_t)b*S_))[tid];
        float4 ms;
        ms.x = mv.x * LOG2E; ms.y = mv.y * LOG2E; ms.z = mv.z * LOG2E; ms.w = mv.w * LOG2E;
        ((float4*)mb)[tid] = ms;
        if (mv.x != 0.f || mv.y != 0.f || mv.z != 0.f || mv.w != 0.f) atomicOr(flag, 1);
    }
    {
        char* b0 = smem;
        *(uint4*)(b0 + woff)               = cK0;
        *(uint4*)(b0 + 4096 + woff)        = cK1;
        *(uint4*)(b0 + 8192 + woff)        = cV0;
        *(uint4*)(b0 + 8192 + 4096 + woff) = cV1;
    }
    __syncthreads();
    const int msk = *flag;

    f32x16 o0 = {}, o1 = {};
    float lacc = 0.f;

    for (int t = 0; t < 16; ++t) {
        uint4 nK0, nK1, nV0, nV1;
        if (t < 15) {
            const size_t ko = (size_t)(t + 1) * 64 * H_;
            const int    vo = (t + 1) * 64;
            nK0 = *(const uint4*)(gK0 + ko);
            nK1 = *(const uint4*)(gK1 + ko);
            nV0 = *(const uint4*)(gV0 + vo);
            nV1 = *(const uint4*)(gV1 + vo);
        }
        char* Ks = smem + (t & 1) * 16384;
        char* Vs = Ks + 8192;

#pragma unroll
        for (int ts = 0; ts < 2; ++ts) {
            // ---- QK^T ----
            f32x16 st = {};
            __builtin_amdgcn_s_setprio(1);
#pragma unroll
            for (int step = 0; step < 4; ++step) {
                bf16x8 ak = *(const bf16x8*)(Ks + (ts*32 + qc)*128 +
                             ((step*32 + hi*16) ^ ((qc & 7) << 4)));
                st = mfma32(ak, qf[step], st);
            }
            __builtin_amdgcn_s_setprio(0);

            // ---- softmax ----
            float pv[16];
            if (msk) {
#pragma unroll
                for (int rq = 0; rq < 4; ++rq) {
                    const float4 bb = *(const float4*)(mb + t*64 + ts*32 + rq*8 + hi*4);
#pragma unroll
                    for (int e = 0; e < 4; ++e)
                        pv[rq*4 + e] = __builtin_amdgcn_exp2f(st[rq*4 + e] + (&bb.x)[e]);
                }
            } else {
#pragma unroll
                for (int r = 0; r < 16; ++r) pv[r] = __builtin_amdgcn_exp2f(st[r]);
            }
#pragma unroll
            for (int r = 0; r < 16; ++r) lacc += pv[r];

            // ---- P->A-frags (cvt_pk + permlane32_swap) + PV ----
#pragma unroll
            for (int half = 0; half < 2; ++half) {
                unsigned w0 = cvt_pk_bf16(pv[half*8 + 0], pv[half*8 + 1]);
                unsigned w1 = cvt_pk_bf16(pv[half*8 + 2], pv[half*8 + 3]);
                unsigned w2 = cvt_pk_bf16(pv[half*8 + 4], pv[half*8 + 5]);
                unsigned w3 = cvt_pk_bf16(pv[half*8 + 6], pv[half*8 + 7]);
                perm32swap(w0, w2);
                perm32swap(w1, w3);
                uint4v fw; fw[0] = w0; fw[1] = w1; fw[2] = w2; fw[3] = w3;
                const bf16x8 pa = __builtin_bit_cast(bf16x8, fw);
                const int scol = (ts*64 + half*32 + hi*16) ^ ((qc & 7) << 4);
                bf16x8 v0 = *(const bf16x8*)(Vs + qc*128        + scol);
                bf16x8 v1 = *(const bf16x8*)(Vs + (32 + qc)*128 + scol);
                __builtin_amdgcn_s_setprio(1);
                o0 = mfma32(pa, v0, o0);
                o1 = mfma32(pa, v1, o1);
                __builtin_amdgcn_s_setprio(0);
            }
        }

        if (t < 15) {
            char* nxt = smem + ((t + 1) & 1) * 16384;
            *(uint4*)(nxt + woff)               = nK0;
            *(uint4*)(nxt + 4096 + woff)        = nK1;
            *(uint4*)(nxt + 8192 + woff)        = nV0;
            *(uint4*)(nxt + 8192 + 4096 + woff) = nV1;
        }
        __syncthreads();
    }

    // ---- epilogue ----
    {
        unsigned la = __builtin_bit_cast(unsigned, lacc);
        unsigned lb = la;
        perm32swap(la, lb);
        const float ltot = __builtin_bit_cast(float, la) + __builtin_bit_cast(float, lb);
        const float linv = 1.f / ltot;
        if (hi == 0) lbuf[w*32 + qc] = linv;
    }
    __syncthreads();
    float4 li[4];
#pragma unroll
    for (int rq = 0; rq < 4; ++rq)
        li[rq] = *(const float4*)(lbuf + w*32 + rq*8 + hi*4);

#pragma unroll
    for (int dt = 0; dt < 2; ++dt) {
        const f32x16& oo = dt ? o1 : o0;
#pragma unroll
        for (int r = 0; r < 16; ++r) {
            const int qrow = (r & 3) + 8*(r >> 2) + 4*hi;
            const float val = oo[r] * (&li[r >> 2].x)[r & 3];
            Octx[(size_t)(b*T_ + q0 + qrow)*H_ + h*64 + dt*32 + qc] = f2bf(val);
        }
    }
}

// ---------------- residual + LayerNorm ----------------
template<int OUTMODE>   // 0: bf16 out, 1: f32 out
__global__ __launch_bounds__(256)
void ln_kernel(const unsigned short* __restrict__ resid,
               const unsigned short* __restrict__ proj,
               const float* __restrict__ gam,
               const float* __restrict__ bet,
               unsigned short* __restrict__ obf,
               float* __restrict__ of32)
{
    __shared__ float red[8];
    const int tid = threadIdx.x;
    const int lane = tid & 63, w = tid >> 6;
    const int i = tid * 4;
    const size_t base = (size_t)blockIdx.x * 1024 + i;
    uint2 rv = *(const uint2*)(resid + base);
    uint2 pv = *(const uint2*)(proj + base);
    float x[4];
    x[0] = bf2f(rv.x & 0xffffu) + bf2f(pv.x & 0xffffu);
    x[1] = bf2f(rv.x >> 16)     + bf2f(pv.x >> 16);
    x[2] = bf2f(rv.y & 0xffffu) + bf2f(pv.y & 0xffffu);
    x[3] = bf2f(rv.y >> 16)     + bf2f(pv.y >> 16);
    float s = x[0] + x[1] + x[2] + x[3];
    float q = x[0]*x[0] + x[1]*x[1] + x[2]*x[2] + x[3]*x[3];
#pragma unroll
    for (int off = 1; off < 64; off <<= 1) {
        s += __shfl_xor(s, off);
        q += __shfl_xor(q, off);
    }
    if (lane == 0) { red[w*2] = s; red[w*2 + 1] = q; }
    __syncthreads();
    s = red[0] + red[2] + red[4] + red[6];
    q = red[1] + red[3] + red[5] + red[7];
    const float mu   = s * (1.f/1024.f);
    const float var  = q * (1.f/1024.f) - mu*mu;
    const float rstd = rsqrtf(var + 1e-12f);
    const float4 gv = *(const float4*)(gam + i);
    const float4 bv = *(const float4*)(bet + i);
    float y[4];
#pragma unroll
    for (int j = 0; j < 4; j++)
        y[j] = (x[j] - mu) * rstd * (&gv.x)[j] + (&bv.x)[j];
    if (OUTMODE == 0) {
        uint2 oo;
        oo.x = (unsigned)f2bf(y[0]) | ((unsigned)f2bf(y[1]) << 16);
        oo.y = (unsigned)f2bf(y[2]) | ((unsigned)f2bf(y[3]) << 16);
        *(uint2*)(obf + base) = oo;
    } else {
        float4 oo; oo.x = y[0]; oo.y = y[1]; oo.z = y[2]; oo.w = y[3];
        *(float4*)(of32 + base) = oo;
    }
}

extern "C" void kernel_launch(void* const* d_in, const int* in_sizes, int n_in,
                              void* d_out, int out_size, void* d_ws, size_t ws_size,
                              hipStream_t stream)
{
    const float* enc   = (const float*)d_in[0];
    const float* dec   = (const float*)d_in[1];
    const float* smask = (const float*)d_in[2];
    const float* tmask = (const float*)d_in[3];
    const float* Wq = (const float*)d_in[4];
    const float* bq = (const float*)d_in[5];
    const float* Wk = (const float*)d_in[6];
    const float* bk = (const float*)d_in[7];
    const float* Wv = (const float*)d_in[8];
    const float* bv = (const float*)d_in[9];
    const float* Wd = (const float*)d_in[10];
    const float* bd = (const float*)d_in[11];
    const float* lng = (const float*)d_in[12];
    const float* lnb = (const float*)d_in[13];
    float* out = (float*)d_out;

    char* ws = (char*)d_ws;
    const size_t MB = 1024ull * 1024ull;
    unsigned short* dec_bf = (unsigned short*)(ws + 0*MB);
    unsigned short* enc_bf = (unsigned short*)(ws + 8*MB);
    unsigned short* Wq_bf  = (unsigned short*)(ws + 16*MB);
    unsigned short* Wk_bf  = (unsigned short*)(ws + 18*MB);
    unsigned short* Wv_bf  = (unsigned short*)(ws + 20*MB);
    unsigned short* Wd_bf  = (unsigned short*)(ws + 22*MB);
    unsigned short* q1  = (unsigned short*)(ws + 24*MB);
    unsigned short* k1  = (unsigned short*)(ws + 32*MB);
    unsigned short* vt1 = (unsigned short*)(ws + 40*MB);
    unsigned short* ek  = (unsigned short*)(ws + 48*MB);
    unsigned short* evt = (unsigned short*)(ws + 56*MB);
    unsigned short* ctx      = dec_bf;   // dec_bf dead after j1
    unsigned short* proj     = enc_bf;   // enc_bf dead after j1
    unsigned short* self_out = k1;       // k1 dead after attn1

    CvtArgs ca;
    ca.src[0] = dec; ca.dst[0] = dec_bf; ca.scale[0] = 1.f;      ca.n4[0] = 1048576;
    ca.src[1] = enc; ca.dst[1] = enc_bf; ca.scale[1] = 1.f;      ca.n4[1] = 1048576;
    ca.src[2] = Wq;  ca.dst[2] = Wq_bf;  ca.scale[2] = 1.f;      ca.n4[2] = 262144;
    ca.src[3] = Wk;  ca.dst[3] = Wk_bf;  ca.scale[3] = SCALE_K;  ca.n4[3] = 262144;
    ca.src[4] = Wv;  ca.dst[4] = Wv_bf;  ca.scale[4] = 1.f;      ca.n4[4] = 262144;
    ca.src[5] = Wd;  ca.dst[5] = Wd_bf;  ca.scale[5] = 1.f;      ca.n4[5] = 262144;
    cvt_multi<<<dim3(4096, 6), 256, 0, stream>>>(ca);

    // merged projections: v-sets write per-head-transposed VT directly
    GemmJob j1;
    j1.A[0] = dec_bf; j1.W[0] = Wq_bf; j1.bias[0] = bq; j1.bs[0] = 1.f;     j1.O[0] = q1; j1.OT[0] = nullptr;
    j1.A[1] = dec_bf; j1.W[1] = Wk_bf; j1.bias[1] = bk; j1.bs[1] = SCALE_K; j1.O[1] = k1; j1.OT[1] = nullptr;
    j1.A[2] = dec_bf; j1.W[2] = Wv_bf; j1.bias[2] = bv; j1.bs[2] = 1.f;     j1.O[2] = nullptr; j1.OT[2] = vt1;
    j1.A[3] = enc_bf; j1.W[3] = Wk_bf; j1.bias[3] = bk; j1.bs[3] = SCALE_K; j1.O[3] = ek; j1.OT[3] = nullptr;
    j1.A[4] = enc_bf; j1.W[4] = Wv_bf; j1.bias[4] = bv; j1.bs[4] = 1.f;     j1.O[4] = nullptr; j1.OT[4] = evt;
    gemm_bf16<<<dim3(32, 40), 256, 0, stream>>>(j1);

    GemmJob jd;
    for (int i = 0; i < 5; i++) {
        jd.A[i] = ctx; jd.W[i] = Wd_bf; jd.bias[i] = bd; jd.bs[i] = 1.f;
        jd.O[i] = proj; jd.OT[i] = nullptr;
    }

    // self-attention
    attn_fused2<<<dim3(64, 8), 256, 0, stream>>>(q1, k1, vt1, tmask, ctx);
    gemm_bf16<<<dim3(32, 8), 256, 0, stream>>>(jd);
    ln_kernel<0><<<4096, 256, 0, stream>>>(q1, proj, lng, lnb, self_out, nullptr);

    // cross-attention (query = self_out directly)
    attn_fused2<<<dim3(64, 8), 256, 0, stream>>>(self_out, ek, evt, smask, ctx);
    gemm_bf16<<<dim3(32, 8), 256, 0, stream>>>(jd);
    ln_kernel<1><<<4096, 256, 0, stream>>>(self_out, proj, lng, lnb, nullptr, out);
}

// Round 8
// 155.305 us; speedup vs baseline: 1.1807x; 1.0682x over previous
//
#include <hip/hip_runtime.h>
#include <stdint.h>

// AlbertSeq2Seq fused pipeline, bf16 MFMA. Round 8:
//  - GEMM: double-buffered LDS (64KB) with early-issue DMA: stage tile t+1 at
//    iteration top into the other buffer, ONE barrier per iter (vmcnt drain now
//    ~1000cyc after issue instead of immediate). Per-set koff/klen added.
//  - jd (Wd proj) split-K: 2 half-K sets -> 512 blocks (2/CU, restores wave
//    overlap); bf16 partials, LN sums resid + projA + projB.
//  - attn / cvt unchanged from round 7.
// Shapes: B=4, T=S=1024, H=1024, heads=16, d=64.

#define B_   4
#define T_   1024
#define S_   1024
#define H_   1024
#define LOG2E 1.44269504088896340736f
#define SCALE_K (0.125f * LOG2E)

typedef __attribute__((ext_vector_type(8)))  __bf16       bf16x8;
typedef __attribute__((ext_vector_type(4)))  float        f32x4;
typedef __attribute__((ext_vector_type(16))) float        f32x16;
typedef __attribute__((ext_vector_type(4)))  unsigned int uint4v;

static __device__ __forceinline__ float bf2f(unsigned int u) {
    return __builtin_bit_cast(float, u << 16);
}
static __device__ __forceinline__ unsigned short f2bf(float f) {
    unsigned int x = __builtin_bit_cast(unsigned int, f);
    return (unsigned short)((x + 0x7fffu + ((x >> 16) & 1u)) >> 16);
}
static __device__ __forceinline__ unsigned int cvt_pk_bf16(float lo, float hi) {
    unsigned int r;
    asm("v_cvt_pk_bf16_f32 %0, %1, %2" : "=v"(r) : "v"(lo), "v"(hi));
    return r;
}
static __device__ __forceinline__ void perm32swap(unsigned int& a, unsigned int& b) {
    asm("v_permlane32_swap_b32 %0, %1" : "+v"(a), "+v"(b));
}
static __device__ __forceinline__ f32x4 mfma16(bf16x8 a, bf16x8 b, f32x4 c) {
    return __builtin_amdgcn_mfma_f32_16x16x32_bf16(a, b, c, 0, 0, 0);
}
static __device__ __forceinline__ f32x16 mfma32(bf16x8 a, bf16x8 b, f32x16 c) {
    return __builtin_amdgcn_mfma_f32_32x32x16_bf16(a, b, c, 0, 0, 0);
}

typedef const __attribute__((address_space(1))) void gv_t;
typedef __attribute__((address_space(3))) void lv_t;
static __device__ __forceinline__ void g2lds16(const void* g, void* l) {
    __builtin_amdgcn_global_load_lds((gv_t*)(size_t)g, (lv_t*)(unsigned int)(size_t)l, 16, 0, 0);
}

// ---------------- fused fp32 -> bf16 convert (6 tensors, 1 launch) ----------------
struct CvtArgs {
    const float* src[6];
    unsigned short* dst[6];
    float scale[6];
    int n4[6];
};
__global__ __launch_bounds__(256)
void cvt_multi(CvtArgs a) {
    const int k = blockIdx.y;
    const int i = blockIdx.x * 256 + threadIdx.x;
    if (i >= a.n4[k]) return;
    const float s = a.scale[k];
    float4 v = ((const float4*)a.src[k])[i];
    uint2 o;
    o.x = (unsigned)f2bf(v.x * s) | ((unsigned)f2bf(v.y * s) << 16);
    o.y = (unsigned)f2bf(v.z * s) | ((unsigned)f2bf(v.w * s) << 16);
    ((uint2*)a.dst[k])[i] = o;
}

// ---------------- GEMM: O[set] = A[set][:, koff:koff+klen] @ W[set]^T(cols) + bias*bs ----------------
// 128x128 tile, BK=64, 4 waves (2x2). Double-buffered LDS; stage(t+1) issued at
// iteration top into buf^1, single __syncthreads per iter (drains after compute).
// If OT[set] != null: per-head transposed output (V -> VT fusion).
struct GemmJob {
    const unsigned short* A[5];
    const unsigned short* W[5];
    const float* bias[5];
    float bs[5];
    unsigned short* O[5];
    unsigned short* OT[5];
    int koff[5];
    int klen[5];
};
__global__ __launch_bounds__(256, 2)
void gemm_bf16(GemmJob job)
{
    __shared__ char smem[65536];   // [buf0: A 16K | B 16K][buf1: A 16K | B 16K]
    const int tid = threadIdx.x;
    const int lane = tid & 63;
    const int w = tid >> 6;
    const int c = lane & 15, g = lane >> 4;
    const int wm = (w >> 1) * 64, wn = (w & 1) * 64;
    const int m0 = blockIdx.x * 128;
    const int set = blockIdx.y >> 3;
    const int n0 = (blockIdx.y & 7) * 128;
    const unsigned short* A    = job.A[set];
    const unsigned short* W    = job.W[set];
    const float* bias          = job.bias[set];
    const float bscale         = job.bs[set];
    unsigned short* O          = job.O[set];
    unsigned short* OT         = job.OT[set];
    const int koff             = job.koff[set];
    const int kend             = koff + job.klen[set];

    f32x4 acc[4][4];
#pragma unroll
    for (int i = 0; i < 4; i++)
#pragma unroll
        for (int j = 0; j < 4; j++) acc[i][j] = (f32x4){0.f, 0.f, 0.f, 0.f};

    const int srow = w * 32 + (lane >> 3);
    const int swzc = ((lane & 7) ^ (lane >> 3)) * 8;
    const unsigned short* gA = A + (size_t)(m0 + srow) * 1024 + swzc;
    const unsigned short* gB = W + (size_t)(n0 + srow) * 1024 + swzc;

    auto stage = [&](int kk, int b) {
        char* dA = smem + b*32768 +         w*4096;
        char* dB = smem + b*32768 + 16384 + w*4096;
#pragma unroll
        for (int q = 0; q < 4; q++) {
            g2lds16(gA + kk + q*8192, dA + q*1024);
            g2lds16(gB + kk + q*8192, dB + q*1024);
        }
    };

    stage(koff, 0);
    __syncthreads();

    int bi = 0;
    for (int kk = koff; kk < kend; kk += 64, bi ^= 1) {
        if (kk + 64 < kend) stage(kk + 64, bi ^ 1);
        const char* As = smem + bi*32768;
        const char* Bs = As + 16384;
#pragma unroll
        for (int ksub = 0; ksub < 2; ksub++) {
            bf16x8 af[4], bfr[4];
#pragma unroll
            for (int t = 0; t < 4; t++) {
                const int ra = wm + t*16 + c;
                const int rb = wn + t*16 + c;
                const int so = ((ksub*4 + g) ^ (c & 7)) << 4;
                af[t]  = *(const bf16x8*)(As + ra*128 + so);
                bfr[t] = *(const bf16x8*)(Bs + rb*128 + so);
            }
#pragma unroll
            for (int i = 0; i < 4; i++)
#pragma unroll
                for (int j = 0; j < 4; j++)
                    acc[i][j] = mfma16(af[i], bfr[j], acc[i][j]);
        }
        __syncthreads();   // all waves done reading buf bi; their next-tile DMA drained
    }

    float bvv[4];
#pragma unroll
    for (int j = 0; j < 4; j++) bvv[j] = bias[n0 + wn + j*16 + c] * bscale;

    if (OT == nullptr) {
        // natural coalesced store via per-wave LDS bounce (4KB region)
        char* eb = smem + w * 4096;
#pragma unroll
        for (int p = 0; p < 2; p++) {
#pragma unroll
            for (int ii = 0; ii < 2; ii++) {
                const int i = p*2 + ii;
#pragma unroll
                for (int j = 0; j < 4; j++)
#pragma unroll
                    for (int r = 0; r < 4; r++)
                        *(unsigned short*)(eb + (ii*16 + g*4 + r)*128 + (c + j*16)*2)
                            = f2bf(acc[i][j][r] + bvv[j]);
            }
            asm volatile("s_waitcnt lgkmcnt(0)" ::: "memory");
#pragma unroll
            for (int it = 0; it < 4; it++) {
                const int lrow = it*8 + (lane >> 3);
                uint4 vv = *(const uint4*)(eb + lrow*128 + (lane & 7)*16);
                *(uint4*)(O + (size_t)(m0 + wm + p*32 + lrow)*1024 + n0 + wn + (lane & 7)*8) = vv;
            }
            if (p == 0) asm volatile("s_waitcnt lgkmcnt(0)" ::: "memory");
        }
    } else {
        // transposed (V->VT) store via transposed bounce ebT[n(64)][m(32)], pitch 72B
        char* ebT = smem + w * 8192;
        const int n_glob = n0 + wn + lane;
        const int hh = n_glob >> 6, dd = n_glob & 63;
        const int bidx = m0 >> 10;
        unsigned short* vout0 = OT + ((size_t)((bidx*16 + hh)*64 + dd))*S_ + (m0 & 1023) + wm;
#pragma unroll
        for (int p = 0; p < 2; p++) {
#pragma unroll
            for (int ii = 0; ii < 2; ii++) {
                const int i = p*2 + ii;
#pragma unroll
                for (int j = 0; j < 4; j++) {
                    uint2 pw;
                    pw.x = (unsigned)f2bf(acc[i][j][0] + bvv[j]) |
                           ((unsigned)f2bf(acc[i][j][1] + bvv[j]) << 16);
                    pw.y = (unsigned)f2bf(acc[i][j][2] + bvv[j]) |
                           ((unsigned)f2bf(acc[i][j][3] + bvv[j]) << 16);
                    *(uint2*)(ebT + (j*16 + c)*72 + (ii*16 + g*4)*2) = pw;
                }
            }
            asm volatile("s_waitcnt lgkmcnt(0)" ::: "memory");
            unsigned short* vout = vout0 + p*32;
#pragma unroll
            for (int q = 0; q < 4; q++) {
                uint2 r0 = *(const uint2*)(ebT + lane*72 + (q*2    )*8);
                uint2 r1 = *(const uint2*)(ebT + lane*72 + (q*2 + 1)*8);
                uint4 vv; vv.x = r0.x; vv.y = r0.y; vv.z = r1.x; vv.w = r1.y;
                *(uint4*)(vout + q*8) = vv;
            }
            if (p == 0) asm volatile("s_waitcnt lgkmcnt(0)" ::: "memory");
        }
    }
}

// ---------------- fused flash attention (R3 structure, XCD-colocated grid) ----------------
// grid (B*NH=64, T/128=8): linear id % 8 == bh % 8 -> q-tiles of one (b,h)
// share an XCD for K/V L2 reuse. K pre-scaled by 0.125*log2e.
__global__ __launch_bounds__(256, 4)
void attn_fused2(const unsigned short* __restrict__ Q,
                 const unsigned short* __restrict__ Kx,
                 const unsigned short* __restrict__ VT,
                 const float* __restrict__ mask,
                 unsigned short* __restrict__ Octx)
{
    __shared__ char smem[32768 + 4096 + 512 + 16];
    float* mb   = (float*)(smem + 32768);
    float* lbuf = (float*)(smem + 32768 + 4096);
    int* flag   = (int*)(smem + 32768 + 4096 + 512);

    const int tid = threadIdx.x;
    const int lane = tid & 63, w = tid >> 6;
    const int qc = lane & 31, hi = lane >> 5;
    const int bh = blockIdx.x, b = bh >> 4, h = bh & 15;
    const int q0 = blockIdx.y * 128 + w * 32;

    const int r0 = tid >> 3, sg = tid & 7;
    const unsigned short* gK0 = Kx + (size_t)(b*S_ + r0)*H_  + h*64 + sg*8;
    const unsigned short* gK1 = gK0 + (size_t)32*H_;
    const unsigned short* gV0 = VT + (size_t)(bh*64 + r0)*S_ + sg*8;
    const unsigned short* gV1 = gV0 + (size_t)32*S_;
    const int woff = r0*128 + ((sg*16) ^ ((r0 & 7) << 4));

    const unsigned short* qptr = Q + (size_t)(b*T_ + q0 + qc)*H_ + h*64 + hi*8;
    bf16x8 qf[4];
#pragma unroll
    for (int s = 0; s < 4; s++) qf[s] = *(const bf16x8*)(qptr + s*16);

    // tile 0 staging
    uint4 cK0 = *(const uint4*)gK0;
    uint4 cK1 = *(const uint4*)gK1;
    uint4 cV0 = *(const uint4*)gV0;
    uint4 cV1 = *(const uint4*)gV1;

    if (tid == 0) *flag = 0;
    __syncthreads();
    {
        float4 mv = ((const float4*)(mask + (size_t)b*S_))[tid];
        float4 ms;
        ms.x = mv.x * LOG2E; ms.y = mv.y * LOG2E; ms.z = mv.z * LOG2E; ms.w = mv.w * LOG2E;
        ((float4*)mb)[tid] = ms;
        if (mv.x != 0.f || mv.y != 0.f || mv.z != 0.f || mv.w != 0.f) atomicOr(flag, 1);
    }
    {
        char* b0 = smem;
        *(uint4*)(b0 + woff)               = cK0;
        *(uint4*)(b0 + 4096 + woff)        = cK1;
        *(uint4*)(b0 + 8192 + woff)        = cV0;
        *(uint4*)(b0 + 8192 + 4096 + woff) = cV1;
    }
    __syncthreads();
    const int msk = *flag;

    f32x16 o0 = {}, o1 = {};
    float lacc = 0.f;

    for (int t = 0; t < 16; ++t) {
        uint4 nK0, nK1, nV0, nV1;
        if (t < 15) {
            const size_t ko = (size_t)(t + 1) * 64 * H_;
            const int    vo = (t + 1) * 64;
            nK0 = *(const uint4*)(gK0 + ko);
            nK1 = *(const uint4*)(gK1 + ko);
            nV0 = *(const uint4*)(gV0 + vo);
            nV1 = *(const uint4*)(gV1 + vo);
        }
        char* Ks = smem + (t & 1) * 16384;
        char* Vs = Ks + 8192;

#pragma unroll
        for (int ts = 0; ts < 2; ++ts) {
            // ---- QK^T ----
            f32x16 st = {};
            __builtin_amdgcn_s_setprio(1);
#pragma unroll
            for (int step = 0; step < 4; ++step) {
                bf16x8 ak = *(const bf16x8*)(Ks + (ts*32 + qc)*128 +
                             ((step*32 + hi*16) ^ ((qc & 7) << 4)));
                st = mfma32(ak, qf[step], st);
            }
            __builtin_amdgcn_s_setprio(0);

            // ---- softmax ----
            float pv[16];
            if (msk) {
#pragma unroll
                for (int rq = 0; rq < 4; ++rq) {
                    const float4 bb = *(const float4*)(mb + t*64 + ts*32 + rq*8 + hi*4);
#pragma unroll
                    for (int e = 0; e < 4; ++e)
                        pv[rq*4 + e] = __builtin_amdgcn_exp2f(st[rq*4 + e] + (&bb.x)[e]);
                }
            } else {
#pragma unroll
                for (int r = 0; r < 16; ++r) pv[r] = __builtin_amdgcn_exp2f(st[r]);
            }
#pragma unroll
            for (int r = 0; r < 16; ++r) lacc += pv[r];

            // ---- P->A-frags (cvt_pk + permlane32_swap) + PV ----
#pragma unroll
            for (int half = 0; half < 2; ++half) {
                unsigned w0 = cvt_pk_bf16(pv[half*8 + 0], pv[half*8 + 1]);
                unsigned w1 = cvt_pk_bf16(pv[half*8 + 2], pv[half*8 + 3]);
                unsigned w2 = cvt_pk_bf16(pv[half*8 + 4], pv[half*8 + 5]);
                unsigned w3 = cvt_pk_bf16(pv[half*8 + 6], pv[half*8 + 7]);
                perm32swap(w0, w2);
                perm32swap(w1, w3);
                uint4v fw; fw[0] = w0; fw[1] = w1; fw[2] = w2; fw[3] = w3;
                const bf16x8 pa = __builtin_bit_cast(bf16x8, fw);
                const int scol = (ts*64 + half*32 + hi*16) ^ ((qc & 7) << 4);
                bf16x8 v0 = *(const bf16x8*)(Vs + qc*128        + scol);
                bf16x8 v1 = *(const bf16x8*)(Vs + (32 + qc)*128 + scol);
                __builtin_amdgcn_s_setprio(1);
                o0 = mfma32(pa, v0, o0);
                o1 = mfma32(pa, v1, o1);
                __builtin_amdgcn_s_setprio(0);
            }
        }

        if (t < 15) {
            char* nxt = smem + ((t + 1) & 1) * 16384;
            *(uint4*)(nxt + woff)               = nK0;
            *(uint4*)(nxt + 4096 + woff)        = nK1;
            *(uint4*)(nxt + 8192 + woff)        = nV0;
            *(uint4*)(nxt + 8192 + 4096 + woff) = nV1;
        }
        __syncthreads();
    }

    // ---- epilogue ----
    {
        unsigned la = __builtin_bit_cast(unsigned, lacc);
        unsigned lb = la;
        perm32swap(la, lb);
        const float ltot = __builtin_bit_cast(float, la) + __builtin_bit_cast(float, lb);
        const float linv = 1.f / ltot;
        if (hi == 0) lbuf[w*32 + qc] = linv;
    }
    __syncthreads();
    float4 li[4];
#pragma unroll
    for (int rq = 0; rq < 4; ++rq)
        li[rq] = *(const float4*)(lbuf + w*32 + rq*8 + hi*4);

#pragma unroll
    for (int dt = 0; dt < 2; ++dt) {
        const f32x16& oo = dt ? o1 : o0;
#pragma unroll
        for (int r = 0; r < 16; ++r) {
            const int qrow = (r & 3) + 8*(r >> 2) + 4*hi;
            const float val = oo[r] * (&li[r >> 2].x)[r & 3];
            Octx[(size_t)(b*T_ + q0 + qrow)*H_ + h*64 + dt*32 + qc] = f2bf(val);
        }
    }
}

// ---------------- residual + LayerNorm (3-input: resid + projA + projB) ----------------
template<int OUTMODE>   // 0: bf16 out, 1: f32 out
__global__ __launch_bounds__(256)
void ln_kernel(const unsigned short* __restrict__ resid,
               const unsigned short* __restrict__ projA,
               const unsigned short* __restrict__ projB,
               const float* __restrict__ gam,
               const float* __restrict__ bet,
               unsigned short* __restrict__ obf,
               float* __restrict__ of32)
{
    __shared__ float red[8];
    const int tid = threadIdx.x;
    const int lane = tid & 63, w = tid >> 6;
    const int i = tid * 4;
    const size_t base = (size_t)blockIdx.x * 1024 + i;
    uint2 rv = *(const uint2*)(resid + base);
    uint2 pv = *(const uint2*)(projA + base);
    uint2 qv = *(const uint2*)(projB + base);
    float x[4];
    x[0] = bf2f(rv.x & 0xffffu) + bf2f(pv.x & 0xffffu) + bf2f(qv.x & 0xffffu);
    x[1] = bf2f(rv.x >> 16)     + bf2f(pv.x >> 16)     + bf2f(qv.x >> 16);
    x[2] = bf2f(rv.y & 0xffffu) + bf2f(pv.y & 0xffffu) + bf2f(qv.y & 0xffffu);
    x[3] = bf2f(rv.y >> 16)     + bf2f(pv.y >> 16)     + bf2f(qv.y >> 16);
    float s = x[0] + x[1] + x[2] + x[3];
    float q = x[0]*x[0] + x[1]*x[1] + x[2]*x[2] + x[3]*x[3];
#pragma unroll
    for (int off = 1; off < 64; off <<= 1) {
        s += __shfl_xor(s, off);
        q += __shfl_xor(q, off);
    }
    if (lane == 0) { red[w*2] = s; red[w*2 + 1] = q; }
    __syncthreads();
    s = red[0] + red[2] + red[4] + red[6];
    q = red[1] + red[3] + red[5] + red[7];
    const float mu   = s * (1.f/1024.f);
    const float var  = q * (1.f/1024.f) - mu*mu;
    const float rstd = rsqrtf(var + 1e-12f);
    const float4 gv = *(const float4*)(gam + i);
    const float4 bv = *(const float4*)(bet + i);
    float y[4];
#pragma unroll
    for (int j = 0; j < 4; j++)
        y[j] = (x[j] - mu) * rstd * (&gv.x)[j] + (&bv.x)[j];
    if (OUTMODE == 0) {
        uint2 oo;
        oo.x = (unsigned)f2bf(y[0]) | ((unsigned)f2bf(y[1]) << 16);
        oo.y = (unsigned)f2bf(y[2]) | ((unsigned)f2bf(y[3]) << 16);
        *(uint2*)(obf + base) = oo;
    } else {
        float4 oo; oo.x = y[0]; oo.y = y[1]; oo.z = y[2]; oo.w = y[3];
        *(float4*)(of32 + base) = oo;
    }
}

extern "C" void kernel_launch(void* const* d_in, const int* in_sizes, int n_in,
                              void* d_out, int out_size, void* d_ws, size_t ws_size,
                              hipStream_t stream)
{
    const float* enc   = (const float*)d_in[0];
    const float* dec   = (const float*)d_in[1];
    const float* smask = (const float*)d_in[2];
    const float* tmask = (const float*)d_in[3];
    const float* Wq = (const float*)d_in[4];
    const float* bq = (const float*)d_in[5];
    const float* Wk = (const float*)d_in[6];
    const float* bk = (const float*)d_in[7];
    const float* Wv = (const float*)d_in[8];
    const float* bv = (const float*)d_in[9];
    const float* Wd = (const float*)d_in[10];
    const float* bd = (const float*)d_in[11];
    const float* lng = (const float*)d_in[12];
    const float* lnb = (const float*)d_in[13];
    float* out = (float*)d_out;

    char* ws = (char*)d_ws;
    const size_t MB = 1024ull * 1024ull;
    unsigned short* dec_bf = (unsigned short*)(ws + 0*MB);
    unsigned short* enc_bf = (unsigned short*)(ws + 8*MB);
    unsigned short* Wq_bf  = (unsigned short*)(ws + 16*MB);
    unsigned short* Wk_bf  = (unsigned short*)(ws + 18*MB);
    unsigned short* Wv_bf  = (unsigned short*)(ws + 20*MB);
    unsigned short* Wd_bf  = (unsigned short*)(ws + 22*MB);
    unsigned short* q1  = (unsigned short*)(ws + 24*MB);
    unsigned short* k1  = (unsigned short*)(ws + 32*MB);
    unsigned short* vt1 = (unsigned short*)(ws + 40*MB);
    unsigned short* ek  = (unsigned short*)(ws + 48*MB);
    unsigned short* evt = (unsigned short*)(ws + 56*MB);
    unsigned short* ctx      = dec_bf;   // dec_bf dead after j1
    unsigned short* proj     = enc_bf;   // enc_bf dead after j1
    unsigned short* projb    = vt1;      // vt1 dead once attn1 done (jd/ln time)
    unsigned short* self_out = k1;       // k1 dead after attn1

    CvtArgs ca;
    ca.src[0] = dec; ca.dst[0] = dec_bf; ca.scale[0] = 1.f;      ca.n4[0] = 1048576;
    ca.src[1] = enc; ca.dst[1] = enc_bf; ca.scale[1] = 1.f;      ca.n4[1] = 1048576;
    ca.src[2] = Wq;  ca.dst[2] = Wq_bf;  ca.scale[2] = 1.f;      ca.n4[2] = 262144;
    ca.src[3] = Wk;  ca.dst[3] = Wk_bf;  ca.scale[3] = SCALE_K;  ca.n4[3] = 262144;
    ca.src[4] = Wv;  ca.dst[4] = Wv_bf;  ca.scale[4] = 1.f;      ca.n4[4] = 262144;
    ca.src[5] = Wd;  ca.dst[5] = Wd_bf;  ca.scale[5] = 1.f;      ca.n4[5] = 262144;
    cvt_multi<<<dim3(4096, 6), 256, 0, stream>>>(ca);

    // merged projections: v-sets write per-head-transposed VT directly
    GemmJob j1;
    j1.A[0] = dec_bf; j1.W[0] = Wq_bf; j1.bias[0] = bq; j1.bs[0] = 1.f;     j1.O[0] = q1; j1.OT[0] = nullptr;
    j1.A[1] = dec_bf; j1.W[1] = Wk_bf; j1.bias[1] = bk; j1.bs[1] = SCALE_K; j1.O[1] = k1; j1.OT[1] = nullptr;
    j1.A[2] = dec_bf; j1.W[2] = Wv_bf; j1.bias[2] = bv; j1.bs[2] = 1.f;     j1.O[2] = nullptr; j1.OT[2] = vt1;
    j1.A[3] = enc_bf; j1.W[3] = Wk_bf; j1.bias[3] = bk; j1.bs[3] = SCALE_K; j1.O[3] = ek; j1.OT[3] = nullptr;
    j1.A[4] = enc_bf; j1.W[4] = Wv_bf; j1.bias[4] = bv; j1.bs[4] = 1.f;     j1.O[4] = nullptr; j1.OT[4] = evt;
    for (int i = 0; i < 5; i++) { j1.koff[i] = 0; j1.klen[i] = 1024; }
    gemm_bf16<<<dim3(32, 40), 256, 0, stream>>>(j1);

    // jd: Wd projection, split-K (2 sets of K=512) -> 512 blocks, partials bf16
    GemmJob jd;
    for (int i = 0; i < 5; i++) {
        jd.A[i] = ctx; jd.W[i] = Wd_bf; jd.bias[i] = bd; jd.bs[i] = 1.f;
        jd.O[i] = proj; jd.OT[i] = nullptr; jd.koff[i] = 0; jd.klen[i] = 512;
    }
    jd.bs[1] = 0.f; jd.O[1] = projb; jd.koff[1] = 512;

    // self-attention
    attn_fused2<<<dim3(64, 8), 256, 0, stream>>>(q1, k1, vt1, tmask, ctx);
    gemm_bf16<<<dim3(32, 16), 256, 0, stream>>>(jd);
    ln_kernel<0><<<4096, 256, 0, stream>>>(q1, proj, projb, lng, lnb, self_out, nullptr);

    // cross-attention (query = self_out directly)
    attn_fused2<<<dim3(64, 8), 256, 0, stream>>>(self_out, ek, evt, smask, ctx);
    gemm_bf16<<<dim3(32, 16), 256, 0, stream>>>(jd);
    ln_kernel<1><<<4096, 256, 0, stream>>>(self_out, proj, projb, lng, lnb, nullptr, out);
}